// Round 1
// baseline (699.150 us; speedup 1.0000x reference)
//
#include <hip/hip_runtime.h>
#include <hip/hip_bf16.h>
#include <math.h>

// Problem: D=8192.
//   s   = sum_{i,j} w[i] * A[i,j] * B[i,j]          (scalar)
//   aw  = tanh(s + b[0])                            (scalar)
//   out = A*aw + B*(1-aw)                           ([D,D] f32)
//
// Two passes, both HBM-bound:
//   pass1: read A,B (512 MB) -> scalar via atomicAdd
//   pass2: read A,B (512 MB) + write out (256 MB); if aw saturates to
//          exactly 1.0f/0.0f (extremely likely: |s| ~ O(80)), out == A or B
//          bit-exactly, so we copy only one input (saves 256 MB of reads).

#define D_DIM 8192
#define ROW_F4 (D_DIM / 4)          // 2048 float4 per row
#define N4 ((long)D_DIM * D_DIM / 4) // 16,777,216 float4 total

__global__ __launch_bounds__(256) void af3_reduce_kernel(
    const float4* __restrict__ A4, const float4* __restrict__ B4,
    const float* __restrict__ w, float* __restrict__ s_out)
{
    float acc = 0.0f;
    const long stride = (long)gridDim.x * blockDim.x;
    for (long i = (long)blockIdx.x * blockDim.x + threadIdx.x; i < N4; i += stride) {
        float4 a = A4[i];
        float4 b = B4[i];
        // row = (i*4)/D = i / 2048 ; wave-uniform (2048 f4/row >> 64 lanes)
        float wi = w[i >> 11];
        float dot = a.x * b.x + a.y * b.y + a.z * b.z + a.w * b.w;
        acc = fmaf(wi, dot, acc);
    }

    // wave (64-lane) butterfly reduce
    #pragma unroll
    for (int off = 32; off > 0; off >>= 1)
        acc += __shfl_down(acc, off, 64);

    __shared__ float lds[4]; // 256 threads = 4 waves
    const int lane = threadIdx.x & 63;
    const int wid  = threadIdx.x >> 6;
    if (lane == 0) lds[wid] = acc;
    __syncthreads();
    if (threadIdx.x == 0) {
        float t = lds[0] + lds[1] + lds[2] + lds[3];
        atomicAdd(s_out, t); // device-scope by default on CDNA
    }
}

__global__ __launch_bounds__(256) void af3_blend_kernel(
    const float4* __restrict__ A4, const float4* __restrict__ B4,
    const float* __restrict__ s_in, const float* __restrict__ bias,
    float4* __restrict__ out4)
{
    const float aw = tanhf(s_in[0] + bias[0]); // uniform scalar, cached read
    const long stride = (long)gridDim.x * blockDim.x;
    long i = (long)blockIdx.x * blockDim.x + threadIdx.x;

    if (aw == 1.0f) {
        // out == A exactly (A*1 + B*0). Skip B reads entirely.
        for (; i < N4; i += stride) out4[i] = A4[i];
    } else if (aw == 0.0f) {
        // out == B exactly.
        for (; i < N4; i += stride) out4[i] = B4[i];
    } else {
        const float om = 1.0f - aw;
        for (; i < N4; i += stride) {
            float4 a = A4[i];
            float4 b = B4[i];
            float4 r;
            r.x = fmaf(a.x, aw, b.x * om);
            r.y = fmaf(a.y, aw, b.y * om);
            r.z = fmaf(a.z, aw, b.z * om);
            r.w = fmaf(a.w, aw, b.w * om);
            out4[i] = r;
        }
    }
}

extern "C" void kernel_launch(void* const* d_in, const int* in_sizes, int n_in,
                              void* d_out, int out_size, void* d_ws, size_t ws_size,
                              hipStream_t stream) {
    const float4* A4 = (const float4*)d_in[0];
    const float4* B4 = (const float4*)d_in[1];
    const float*  w  = (const float*)d_in[2];
    const float*  b  = (const float*)d_in[3];
    float4* out4 = (float4*)d_out;
    float*  s_ws = (float*)d_ws;

    // d_ws is poisoned to 0xAA before every call — zero the accumulator.
    hipMemsetAsync(s_ws, 0, sizeof(float), stream);

    // Pass 1: global reduction. 2048 blocks x 256 threads, grid-stride.
    af3_reduce_kernel<<<2048, 256, 0, stream>>>(A4, B4, w, s_ws);

    // Pass 2: blend / copy. 4096 blocks x 256 threads, grid-stride.
    af3_blend_kernel<<<4096, 256, 0, stream>>>(A4, B4, s_ws, b, out4);
}